// Round 13
// baseline (111.588 us; speedup 1.0000x reference)
//
#include <hip/hip_runtime.h>
#include <hip/hip_bf16.h>
#include <hip/hip_fp8.h>
#include <stdint.h>

#define NB 8192
#define ND 1024
#define SCALE 20.0f        // 1/TEMPERATURE
#define PRESCALE 16.0f     // fp8 pre-scale; sim comes out x256
#define EXPSCALE (SCALE / (PRESCALE * PRESCALE))

typedef __bf16 bf16x8 __attribute__((ext_vector_type(8)));
typedef float  f32x4  __attribute__((ext_vector_type(4)));
typedef float  f32x16 __attribute__((ext_vector_type(16)));
typedef int    i32x4  __attribute__((ext_vector_type(4)));
typedef int    i32x8  __attribute__((ext_vector_type(8)));

#define SC1 0x7F7F7F7F     // E8M0 scale bytes = 127 -> 2^0 = 1.0 (all byte-sels safe)

// ---------------- input-format detection (device-side, deterministic) -------
__device__ inline void detect_formats(const void* rel_raw, const void* ist_raw,
                                      int& rel64, int& bmode) {
  const unsigned int* r = (const unsigned int*)rel_raw;
  int is64 = 1;
  for (int i = 1; i < 256; i += 2) {
    if (r[i] != 0u) { is64 = 0; break; }
  }
  rel64 = is64;
  const unsigned int* t = (const unsigned int*)ist_raw;
  bool sawf = false, sawbig = false;
  for (int i = 0; i < 64; ++i) {
    unsigned int w = t[i];
    if (w == 0x3F800000u) sawf = true;
    else if (w > 1u) sawbig = true;
  }
  bmode = sawf ? 2 : (sawbig ? 1 : 0);
}

__device__ inline int decode_key(const void* rel_raw, const void* ist_raw,
                                 int rel64, int bmode, int i) {
  const int* r32 = (const int*)rel_raw;
  int r = rel64 ? r32[2 * i] : r32[i];
  int truth;
  if (bmode == 1)      truth = (((const unsigned char*)ist_raw)[i] != 0);
  else if (bmode == 2) truth = (((const float*)ist_raw)[i] != 0.0f);
  else                 truth = (((const int*)ist_raw)[i] != 0);
  return truth ? r : -1;
}

__device__ inline bf16x8 cvt8(const float4& a, const float4& b) {
  bf16x8 v;
  v[0] = (__bf16)a.x; v[1] = (__bf16)a.y; v[2] = (__bf16)a.z; v[3] = (__bf16)a.w;
  v[4] = (__bf16)b.x; v[5] = (__bf16)b.y; v[6] = (__bf16)b.z; v[7] = (__bf16)b.w;
  return v;
}

__device__ inline unsigned long long cvt8f8(const float4& a, const float4& b) {
  float v[8] = {a.x, a.y, a.z, a.w, b.x, b.y, b.z, b.w};
  unsigned long long pk = 0;
#pragma unroll
  for (int i = 0; i < 8; ++i) {
    __hip_fp8_e4m3 h(v[i] * PRESCALE);
    pk |= (unsigned long long)(unsigned char)h.__x << (8 * i);
  }
  return pk;
}

// ---------------- prep: f32->fp8 convert (LINEAR k) + init ------------------
// MX 32x32x64 fragments read 32 contiguous k-bytes per lane, so the global
// fp8 buffer is plain row-major (r11/r12's k-pairing removed).
__global__ void prep_kernel(const float* __restrict__ emb,
                            const void* __restrict__ rel_raw,
                            const void* __restrict__ ist_raw,
                            unsigned char* __restrict__ emb8,
                            float* __restrict__ sum_exp,
                            float* __restrict__ numer,
                            int* __restrict__ key) {
  int tid = blockIdx.x * 256 + threadIdx.x;
  size_t base = (size_t)tid * 8;
  if (base < (size_t)NB * ND) {
    float4 a = *(const float4*)(emb + base);
    float4 b = *(const float4*)(emb + base + 4);
    *(unsigned long long*)(emb8 + base) = cvt8f8(a, b);
  }
  if (tid < NB) { sum_exp[tid] = 0.f; numer[tid] = 0.f; }
  __shared__ int s_rel64, s_bmode;
  if (blockIdx.x < 32) {                 // block-uniform branch
    if (threadIdx.x == 0) {
      int a, b; detect_formats(rel_raw, ist_raw, a, b);
      s_rel64 = a; s_bmode = b;
    }
    __syncthreads();
    int i = blockIdx.x * 256 + threadIdx.x;   // < 8192
    key[i] = decode_key(rel_raw, ist_raw, s_rel64, s_bmode, i);
  }
}

// small-ws fallback prep (no fp8 buffer)
__global__ void prep_small_kernel(const void* __restrict__ rel_raw,
                                  const void* __restrict__ ist_raw,
                                  float* __restrict__ sum_exp,
                                  float* __restrict__ numer,
                                  int* __restrict__ key) {
  int i = blockIdx.x * 256 + threadIdx.x;     // 32 blocks -> 8192
  sum_exp[i] = 0.f; numer[i] = 0.f;
  __shared__ int s_rel64, s_bmode;
  if (threadIdx.x == 0) {
    int a, b; detect_formats(rel_raw, ist_raw, a, b);
    s_rel64 = a; s_bmode = b;
  }
  __syncthreads();
  key[i] = decode_key(rel_raw, ist_raw, s_rel64, s_bmode, i);
}

// ============================================================================
// Fused symmetric GEMM, MX-scaled fp8 (mfma_scale_f32_32x32x64, scales = 1.0):
// pipeline byte-compatible with r12 — BK=64 phases, triple-buffered LDS,
// counted vmcnt(4), setprio, XOR slot swizzle f(r) = (r>>1)&3 (0 conflicts,
// measured r12; the 32x32 fragment read derives to the SAME condition).
// Per wave: 64x64 output = 2x2 frags of 32x32; per phase 8 ds_read_b128 +
// 4 MFMA (each K=64 at 2x fp8 rate) — half of r12's MFMA cycles.
// ============================================================================

__global__ __launch_bounds__(256, 4)
void gemm_mx_kernel(const unsigned char* __restrict__ emb8,
                    const int* __restrict__ key,
                    float* __restrict__ sum_exp,
                    float* __restrict__ numer) {
  __shared__ unsigned char sT[3][2][8192];   // [buf][op A=0/B=1]  48 KB
  __shared__ int keyR[128], keyC[128];

  // XCD-chunked bijective swizzle (2080 = 8 * 260), then triangular decode
  const int bid = blockIdx.x;
  const int t = (bid & 7) * 260 + (bid >> 3);
  int r = (int)((sqrtf(8.f * (float)t + 1.f) - 1.f) * 0.5f);
  while ((r + 1) * (r + 2) / 2 <= t) ++r;
  while (r * (r + 1) / 2 > t) --r;
  const int bx = r, by = t - r * (r + 1) / 2;
  const bool diag = (bx == by);
  const int rowBase = by * 128, colBase = bx * 128;

  const int tid = threadIdx.x;
  const int wid = tid >> 6;     // 0..3
  const int l   = tid & 63;
  const int wr  = wid >> 1;     // wave row (0..1)
  const int wc  = wid & 1;      // wave col (0..1)
  const int la  = l & 31;       // 32x32 fragment col
  const int h2  = (l >> 5) << 1;   // k-granule pair base {0,2}

  // per-frag LDS read offsets: row r -> byte (r>>4)*1024 + (r&15)*64;
  // granules (h2, h2+1) at slots g ^ ((r>>1)&3)  [r12 swizzle, 0-conflict]
  int aOffL[2][2], bOffL[2][2];
#pragma unroll
  for (int i = 0; i < 2; ++i) {
    int rr = wr * 64 + i * 32 + la;
    int rbyte = ((rr >> 4) << 10) + ((rr & 15) << 6);
    int X = (rr >> 1) & 3;
    aOffL[i][0] = rbyte + ((h2 ^ X) << 4);
    aOffL[i][1] = rbyte + (((h2 + 1) ^ X) << 4);
    int cc = wc * 64 + i * 32 + la;
    int cbyte = ((cc >> 4) << 10) + ((cc & 15) << 6);
    int Xc = (cc >> 1) & 3;
    bOffL[i][0] = cbyte + ((h2 ^ Xc) << 4);
    bOffL[i][1] = cbyte + (((h2 + 1) ^ Xc) << 4);
  }

  // staging source (identical to r12): lane l -> row l>>2, global chunk
  // (l&3) ^ ((l>>3)&3); LDS dest lane-linear
  const int srow = l >> 2;
  const int scol = (((l & 3) ^ ((l >> 3) & 3)) * 16);

  if (tid < 128) keyR[tid] = key[rowBase + tid];
  else           keyC[tid - 128] = key[colBase + tid - 128];
  asm volatile("" ::: "memory");   // pin key ds_writes before the pipeline

  const size_t aOff0 = (size_t)(rowBase + (wid * 2 + 0) * 16 + srow) * ND + scol;
  const size_t aOff1 = (size_t)(rowBase + (wid * 2 + 1) * 16 + srow) * ND + scol;
  const size_t bOff0 = (size_t)(colBase + (wid * 2 + 0) * 16 + srow) * ND + scol;
  const size_t bOff1 = (size_t)(colBase + (wid * 2 + 1) * 16 + srow) * ND + scol;
  const int dst0 = (wid * 2 + 0) * 1024 + l * 16;
  const int dst1 = (wid * 2 + 1) * 1024 + l * 16;

#define STAGE(buf, k0)                                                         \
  do {                                                                         \
    __builtin_amdgcn_global_load_lds(                                          \
        (const __attribute__((address_space(1))) void*)(emb8 + aOff0 + (k0)),  \
        (__attribute__((address_space(3))) void*)&sT[buf][0][dst0], 16, 0, 0); \
    __builtin_amdgcn_global_load_lds(                                          \
        (const __attribute__((address_space(1))) void*)(emb8 + aOff1 + (k0)),  \
        (__attribute__((address_space(3))) void*)&sT[buf][0][dst1], 16, 0, 0); \
    __builtin_amdgcn_global_load_lds(                                          \
        (const __attribute__((address_space(1))) void*)(emb8 + bOff0 + (k0)),  \
        (__attribute__((address_space(3))) void*)&sT[buf][1][dst0], 16, 0, 0); \
    __builtin_amdgcn_global_load_lds(                                          \
        (const __attribute__((address_space(1))) void*)(emb8 + bOff1 + (k0)),  \
        (__attribute__((address_space(3))) void*)&sT[buf][1][dst1], 16, 0, 0); \
  } while (0)

  // prologue: stage K-tile 0 into buf 0
  STAGE(0, 0);

  f32x16 acc32[2][2] = {};
  int rb = 0, wb = 1;            // read buffer, write buffer (wave-uniform)

#pragma unroll 1
  for (int kt = 0; kt < 16; ++kt) {
    if (kt < 15) {               // stage K-tile kt+1 into buf wb
      STAGE(wb, (kt + 1) * 64);
      asm volatile("s_waitcnt vmcnt(4) lgkmcnt(0)" ::: "memory");
    } else {
      asm volatile("s_waitcnt vmcnt(0) lgkmcnt(0)" ::: "memory");
    }
    __builtin_amdgcn_s_barrier();
    asm volatile("" ::: "memory");   // keep ds_reads below the barrier

    const unsigned char* cA = &sT[rb][0][0];
    const unsigned char* cB = &sT[rb][1][0];
    i32x8 a8[2], b8[2];
#pragma unroll
    for (int i = 0; i < 2; ++i) {
      i32x4 lo = *(const i32x4*)&cA[aOffL[i][0]];
      i32x4 hi = *(const i32x4*)&cA[aOffL[i][1]];
      a8[i] = __builtin_shufflevector(lo, hi, 0, 1, 2, 3, 4, 5, 6, 7);
    }
#pragma unroll
    for (int j = 0; j < 2; ++j) {
      i32x4 lo = *(const i32x4*)&cB[bOffL[j][0]];
      i32x4 hi = *(const i32x4*)&cB[bOffL[j][1]];
      b8[j] = __builtin_shufflevector(lo, hi, 0, 1, 2, 3, 4, 5, 6, 7);
    }
    __builtin_amdgcn_s_setprio(1);
#pragma unroll
    for (int i = 0; i < 2; ++i)
#pragma unroll
      for (int j = 0; j < 2; ++j)
        acc32[i][j] = __builtin_amdgcn_mfma_scale_f32_32x32x64_f8f6f4(
            a8[i], b8[j], acc32[i][j], 0, 0, 0, SC1, 0, SC1);
    __builtin_amdgcn_s_setprio(0);

    rb = (rb == 2) ? 0 : rb + 1;
    wb = (wb == 2) ? 0 : wb + 1;
  }
#undef STAGE

  // ---- epilogue: 32x32 C/D layout col = l&31, row = (reg&3)+8*(reg>>2)+4*(l>>5)
  float csum[2] = {0.f, 0.f};
  float cnum[2] = {0.f, 0.f};
#pragma unroll
  for (int i = 0; i < 2; ++i) {
#pragma unroll
    for (int reg = 0; reg < 16; ++reg) {
      int row = (reg & 3) + 8 * (reg >> 2) + 4 * (l >> 5);
      int li = wr * 64 + i * 32 + row;
      int gi = rowBase + li;
      int krow = keyR[li];
      float se = 0.f, nu = 0.f;
#pragma unroll
      for (int j = 0; j < 2; ++j) {
        int lj = wc * 64 + j * 32 + la;
        int gj = colBase + lj;
        float e = __expf(acc32[i][j][reg] * EXPSCALE);
        if (gi == gj) e = 0.f;          // only possible on diagonal tiles
        bool match = (krow >= 0) && (krow == keyC[lj]);
        se += e;
        if (match) nu += e;
        if (!diag) {
          csum[j] += e;
          if (match) cnum[j] += e;
        }
      }
      // row-sum reduce across the 32 cols (lanes sharing l>>5)
#pragma unroll
      for (int off = 1; off < 32; off <<= 1) {
        se += __shfl_xor(se, off);
        nu += __shfl_xor(nu, off);
      }
      if (la == 0) {                    // lanes 0 and 32: two distinct rows
        atomicAdd(&sum_exp[gi], se);
        if (nu != 0.f) atomicAdd(&numer[gi], nu);
      }
    }
  }
  if (!diag) {
#pragma unroll
    for (int j = 0; j < 2; ++j) {
      csum[j] += __shfl_xor(csum[j], 32);
      cnum[j] += __shfl_xor(cnum[j], 32);
    }
    if (l < 32) {
#pragma unroll
      for (int j = 0; j < 2; ++j) {
        int gj = colBase + wc * 64 + j * 32 + l;
        atomicAdd(&sum_exp[gj], csum[j]);
        if (cnum[j] != 0.f) atomicAdd(&numer[gj], cnum[j]);
      }
    }
  }
}

// ---------------- fallback 128^2 fused kernel (small-ws path, bf16) --------
__global__ __launch_bounds__(256, 4)
void gemm_fused_f32_kernel(const float* __restrict__ embF,
                           const int* __restrict__ key,
                           float* __restrict__ sum_exp,
                           float* __restrict__ numer) {
  __shared__ __bf16 sA[128 * 64];
  __shared__ __bf16 sB[128 * 64];
  __shared__ int keyR[128], keyC[128];

  const int t = blockIdx.x;
  int r = (int)((sqrtf(8.f * (float)t + 1.f) - 1.f) * 0.5f);
  while ((r + 1) * (r + 2) / 2 <= t) ++r;
  while (r * (r + 1) / 2 > t) --r;
  const int bx = r;
  const int by = t - r * (r + 1) / 2;
  const bool diag = (bx == by);

  const int tid = threadIdx.x;
  const int wid = tid >> 6;
  const int l   = tid & 63;
  const int wr  = wid >> 1;
  const int wc  = wid & 1;
  const int rowBase = by * 128;
  const int colBase = bx * 128;

  if (tid < 128) keyR[tid] = key[rowBase + tid];
  else           keyC[tid - 128] = key[colBase + tid - 128];

  f32x4 acc[4][4] = {};

  for (int k0 = 0; k0 < ND; k0 += 64) {
    __syncthreads();
#pragma unroll
    for (int c = 0; c < 4; ++c) {
      int chunk = tid + c * 256;
      int row = chunk >> 3;
      int ko  = (chunk & 7) * 8;
      const float* gfa = embF + (size_t)(rowBase + row) * ND + k0 + ko;
      const float* gfb = embF + (size_t)(colBase + row) * ND + k0 + ko;
      float4 a0 = *(const float4*)gfa;
      float4 a1 = *(const float4*)(gfa + 4);
      float4 b0 = *(const float4*)gfb;
      float4 b1 = *(const float4*)(gfb + 4);
      *(bf16x8*)&sA[row * 64 + ko] = cvt8(a0, a1);
      *(bf16x8*)&sB[row * 64 + ko] = cvt8(b0, b1);
    }
    __syncthreads();

#pragma unroll
    for (int kk = 0; kk < 2; ++kk) {
      bf16x8 af[4], bfr[4];
#pragma unroll
      for (int m = 0; m < 4; ++m)
        af[m] = *(const bf16x8*)&sA[(wr * 64 + m * 16 + (l & 15)) * 64 + kk * 32 + (l >> 4) * 8];
#pragma unroll
      for (int n = 0; n < 4; ++n)
        bfr[n] = *(const bf16x8*)&sB[(wc * 64 + n * 16 + (l & 15)) * 64 + kk * 32 + (l >> 4) * 8];
#pragma unroll
      for (int m = 0; m < 4; ++m)
#pragma unroll
        for (int n = 0; n < 4; ++n)
          acc[m][n] = __builtin_amdgcn_mfma_f32_16x16x32_bf16(af[m], bfr[n], acc[m][n], 0, 0, 0);
    }
  }

  float cse[4] = {0.f, 0.f, 0.f, 0.f};
  float cnu[4] = {0.f, 0.f, 0.f, 0.f};
#pragma unroll
  for (int m = 0; m < 4; ++m) {
#pragma unroll
    for (int r4 = 0; r4 < 4; ++r4) {
      int li = wr * 64 + m * 16 + (l >> 4) * 4 + r4;
      int gi = rowBase + li;
      int krow = keyR[li];
      float se = 0.f, nu = 0.f;
#pragma unroll
      for (int n = 0; n < 4; ++n) {
        int lj = wc * 64 + n * 16 + (l & 15);
        int gj = colBase + lj;
        float e = __expf(acc[m][n][r4] * SCALE);
        if (gi == gj) e = 0.f;
        bool match = (krow >= 0) && (krow == keyC[lj]);
        se += e;
        if (match) nu += e;
        if (!diag) {
          cse[n] += e;
          if (match) cnu[n] += e;
        }
      }
#pragma unroll
      for (int off = 8; off; off >>= 1) {
        se += __shfl_xor(se, off, 16);
        nu += __shfl_xor(nu, off, 16);
      }
      if ((l & 15) == 0) {
        atomicAdd(&sum_exp[gi], se);
        if (nu != 0.f) atomicAdd(&numer[gi], nu);
      }
    }
  }
  if (!diag) {
#pragma unroll
    for (int n = 0; n < 4; ++n) {
      cse[n] += __shfl_xor(cse[n], 16);
      cse[n] += __shfl_xor(cse[n], 32);
      cnu[n] += __shfl_xor(cnu[n], 16);
      cnu[n] += __shfl_xor(cnu[n], 32);
    }
    if (l < 16) {
#pragma unroll
      for (int n = 0; n < 4; ++n) {
        int gj = colBase + wc * 64 + n * 16 + l;
        atomicAdd(&sum_exp[gj], cse[n]);
        if (cnu[n] != 0.f) atomicAdd(&numer[gj], cnu[n]);
      }
    }
  }
}

// ---------------- finalize: histogram -> has_pos, losses, reductions -------
__global__ void finalize_kernel(const float* __restrict__ sum_exp,
                                const float* __restrict__ numer,
                                const int* __restrict__ key,
                                float* __restrict__ out) {
  __shared__ int cnt[128];
  __shared__ float wsum[16];
  __shared__ int wcnt[16];
  int tid = threadIdx.x;      // 1024 threads
  if (tid < 128) cnt[tid] = 0;
  __syncthreads();
  for (int i = tid; i < NB; i += 1024) {
    int k = key[i];
    if (k >= 0) atomicAdd(&cnt[k], 1);
  }
  __syncthreads();
  float ls = 0.f; int np = 0;
  for (int i = tid; i < NB; i += 1024) {
    int k = key[i];
    if (k >= 0 && cnt[k] >= 2) {
      np++;
      ls += logf(sum_exp[i] + 1e-8f) - logf(numer[i]);
    }
  }
  for (int off = 32; off; off >>= 1) {
    ls += __shfl_down(ls, off, 64);
    np += __shfl_down(np, off, 64);
  }
  int w = tid >> 6;
  if ((tid & 63) == 0) { wsum[w] = ls; wcnt[w] = np; }
  __syncthreads();
  if (tid == 0) {
    float s = 0.f; int n = 0;
    for (int i = 0; i < 16; ++i) { s += wsum[i]; n += wcnt[i]; }
    out[0] = (n > 0) ? (s / (float)n) : 0.f;
    out[1] = (float)n;
  }
}

// ---------------------------------------------------------------------------
#define NT128 64
#define NTRI128 (NT128 * (NT128 + 1) / 2) // 2080

extern "C" void kernel_launch(void* const* d_in, const int* in_sizes, int n_in,
                              void* d_out, int out_size, void* d_ws, size_t ws_size,
                              hipStream_t stream) {
  const float* emb = (const float*)d_in[0];
  const void* rel  = d_in[1];
  const void* ist  = d_in[2];
  float* out = (float*)d_out;

  const size_t emb8Bytes = (size_t)NB * ND;      // 8 MiB fp8
  const size_t smallBytes = (size_t)NB * 4 * 3;  // 96 KiB

  char* ws = (char*)d_ws;
  if (ws_size >= emb8Bytes + smallBytes) {
    unsigned char* emb8 = (unsigned char*)ws;
    float* sum_exp = (float*)(ws + emb8Bytes);
    float* numer   = sum_exp + NB;
    int*   key     = (int*)(numer + NB);
    prep_kernel<<<4096, 256, 0, stream>>>(emb, rel, ist, emb8, sum_exp, numer, key);
    gemm_mx_kernel<<<NTRI128, 256, 0, stream>>>(emb8, key, sum_exp, numer);
    finalize_kernel<<<1, 1024, 0, stream>>>(sum_exp, numer, key, out);
  } else {
    float* sum_exp = (float*)ws;
    float* numer   = sum_exp + NB;
    int*   key     = (int*)(numer + NB);
    prep_small_kernel<<<32, 256, 0, stream>>>(rel, ist, sum_exp, numer, key);
    gemm_fused_f32_kernel<<<NTRI128, 256, 0, stream>>>(emb, key, sum_exp, numer);
    finalize_kernel<<<1, 1024, 0, stream>>>(sum_exp, numer, key, out);
  }
}

// Round 14
// 100.379 us; speedup vs baseline: 1.1117x; 1.1117x over previous
//
#include <hip/hip_runtime.h>
#include <hip/hip_bf16.h>
#include <hip/hip_fp8.h>
#include <stdint.h>

#define NB 8192
#define ND 1024
#define SCALE 20.0f        // 1/TEMPERATURE
#define PRESCALE 16.0f     // fp8 pre-scale; sim comes out x256
#define EXPSCALE (SCALE / (PRESCALE * PRESCALE))

typedef __bf16 bf16x8 __attribute__((ext_vector_type(8)));
typedef float  f32x4  __attribute__((ext_vector_type(4)));
typedef long   lx2    __attribute__((ext_vector_type(2)));

// ---------------- input-format detection (device-side, deterministic) -------
__device__ inline void detect_formats(const void* rel_raw, const void* ist_raw,
                                      int& rel64, int& bmode) {
  const unsigned int* r = (const unsigned int*)rel_raw;
  int is64 = 1;
  for (int i = 1; i < 256; i += 2) {
    if (r[i] != 0u) { is64 = 0; break; }
  }
  rel64 = is64;
  const unsigned int* t = (const unsigned int*)ist_raw;
  bool sawf = false, sawbig = false;
  for (int i = 0; i < 64; ++i) {
    unsigned int w = t[i];
    if (w == 0x3F800000u) sawf = true;
    else if (w > 1u) sawbig = true;
  }
  bmode = sawf ? 2 : (sawbig ? 1 : 0);
}

__device__ inline int decode_key(const void* rel_raw, const void* ist_raw,
                                 int rel64, int bmode, int i) {
  const int* r32 = (const int*)rel_raw;
  int r = rel64 ? r32[2 * i] : r32[i];
  int truth;
  if (bmode == 1)      truth = (((const unsigned char*)ist_raw)[i] != 0);
  else if (bmode == 2) truth = (((const float*)ist_raw)[i] != 0.0f);
  else                 truth = (((const int*)ist_raw)[i] != 0);
  return truth ? r : -1;
}

__device__ inline bf16x8 cvt8(const float4& a, const float4& b) {
  bf16x8 v;
  v[0] = (__bf16)a.x; v[1] = (__bf16)a.y; v[2] = (__bf16)a.z; v[3] = (__bf16)a.w;
  v[4] = (__bf16)b.x; v[5] = (__bf16)b.y; v[6] = (__bf16)b.z; v[7] = (__bf16)b.w;
  return v;
}

// HW-packed f32->fp8 conversion where available (v_cvt_pk_fp8_f32: 2 floats
// -> 2 OCP e4m3 bytes per instruction); byte order identical to the scalar
// fallback (v[i] at byte i).
__device__ inline unsigned long long cvt8f8(const float4& a, const float4& b) {
#if __has_builtin(__builtin_amdgcn_cvt_pk_fp8_f32)
  int lo = 0, hi = 0;
  lo = __builtin_amdgcn_cvt_pk_fp8_f32(a.x * PRESCALE, a.y * PRESCALE, lo, false);
  lo = __builtin_amdgcn_cvt_pk_fp8_f32(a.z * PRESCALE, a.w * PRESCALE, lo, true);
  hi = __builtin_amdgcn_cvt_pk_fp8_f32(b.x * PRESCALE, b.y * PRESCALE, hi, false);
  hi = __builtin_amdgcn_cvt_pk_fp8_f32(b.z * PRESCALE, b.w * PRESCALE, hi, true);
  return ((unsigned long long)(unsigned int)hi << 32) | (unsigned int)lo;
#else
  float v[8] = {a.x, a.y, a.z, a.w, b.x, b.y, b.z, b.w};
  unsigned long long pk = 0;
#pragma unroll
  for (int i = 0; i < 8; ++i) {
    __hip_fp8_e4m3 h(v[i] * PRESCALE);
    pk |= (unsigned long long)(unsigned char)h.__x << (8 * i);
  }
  return pk;
#endif
}

// ---------------- prep: f32->fp8 convert (k-paired layout) + init -----------
// Within each 64-k block, 8B units are stored [u0,u4,u1,u5,u2,u6,u3,u7]: one
// 16B chunk s holds BOTH K-halves' unit s -> the GEMM reads fragments as
// ds_read_b128.  A and B share the permutation, so MFMA dot products are
// unaffected (k-order commutes).
__global__ void prep_kernel(const float* __restrict__ emb,
                            const void* __restrict__ rel_raw,
                            const void* __restrict__ ist_raw,
                            unsigned char* __restrict__ emb8,
                            float* __restrict__ sum_exp,
                            float* __restrict__ numer,
                            int* __restrict__ key) {
  int tid = blockIdx.x * 256 + threadIdx.x;
  size_t base = (size_t)tid * 8;
  if (base < (size_t)NB * ND) {
    float4 a = *(const float4*)(emb + base);
    float4 b = *(const float4*)(emb + base + 4);
    int u = (int)((base >> 3) & 7);                   // 8B unit within 64-blk
    size_t dest = (base & ~(size_t)63) | ((size_t)(2 * (u & 3) + (u >> 2)) << 3);
    *(unsigned long long*)(emb8 + dest) = cvt8f8(a, b);
  }
  if (tid < NB) { sum_exp[tid] = 0.f; numer[tid] = 0.f; }
  __shared__ int s_rel64, s_bmode;
  if (blockIdx.x < 32) {                 // block-uniform branch
    if (threadIdx.x == 0) {
      int a, b; detect_formats(rel_raw, ist_raw, a, b);
      s_rel64 = a; s_bmode = b;
    }
    __syncthreads();
    int i = blockIdx.x * 256 + threadIdx.x;   // < 8192
    key[i] = decode_key(rel_raw, ist_raw, s_rel64, s_bmode, i);
  }
}

// small-ws fallback prep (no fp8 buffer)
__global__ void prep_small_kernel(const void* __restrict__ rel_raw,
                                  const void* __restrict__ ist_raw,
                                  float* __restrict__ sum_exp,
                                  float* __restrict__ numer,
                                  int* __restrict__ key) {
  int i = blockIdx.x * 256 + threadIdx.x;     // 32 blocks -> 8192
  sum_exp[i] = 0.f; numer[i] = 0.f;
  __shared__ int s_rel64, s_bmode;
  if (threadIdx.x == 0) {
    int a, b; detect_formats(rel_raw, ist_raw, a, b);
    s_rel64 = a; s_bmode = b;
  }
  __syncthreads();
  key[i] = decode_key(rel_raw, ist_raw, s_rel64, s_bmode, i);
}

// ============================================================================
// Fused symmetric GEMM, fp8, BK=64 phases, triple-buffered, counted vmcnt(4),
// setprio, k-paired global buffer + r5-style XOR slot swizzle:
//   LDS slot p of row r holds global chunk p ^ X(r), X(r) = (r>>1)&3.
//   Read (quarter q, row r): slot q ^ X(r) -> 0 excess bank conflicts
//   (measured: r12 SQ_LDS_BANK_CONFLICT = 0 with this exact pattern).
//   Staging source: lane l fetches chunk (l&3) ^ ((l>>3)&3) of row l>>2;
//   LDS dest stays lane-linear (global_load_lds requirement).
// Phase kt: STAGE(K[kt+1] -> buf[(kt+1)%3], 4 loads);
//           s_waitcnt vmcnt(4) lgkmcnt(0); s_barrier;
//           8 x ds_read_b128; setprio(1); 32 MFMA (lo then hi); setprio(0).
// Best measured configuration of the session (r12: 86 us GEMM, 100.5 total).
// ============================================================================

__global__ __launch_bounds__(256, 4)
void gemm_f8v_kernel(const unsigned char* __restrict__ emb8,
                     const int* __restrict__ key,
                     float* __restrict__ sum_exp,
                     float* __restrict__ numer) {
  __shared__ unsigned char sT[3][2][8192];   // [buf][op A=0/B=1]  48 KB
  __shared__ int keyR[128], keyC[128];

  // XCD-chunked bijective swizzle (2080 = 8 * 260), then triangular decode
  const int bid = blockIdx.x;
  const int t = (bid & 7) * 260 + (bid >> 3);
  int r = (int)((sqrtf(8.f * (float)t + 1.f) - 1.f) * 0.5f);
  while ((r + 1) * (r + 2) / 2 <= t) ++r;
  while (r * (r + 1) / 2 > t) --r;
  const int bx = r, by = t - r * (r + 1) / 2;
  const bool diag = (bx == by);
  const int rowBase = by * 128, colBase = bx * 128;

  const int tid = threadIdx.x;
  const int wid = tid >> 6;     // 0..3
  const int l   = tid & 63;
  const int wr  = wid >> 1;     // wave row (0..1)
  const int wc  = wid & 1;      // wave col (0..1)

  // swizzled fragment offset: row = l&15, quarter q = l>>4, slot = q ^ X(row)
  const int fragOff = (l & 15) * 64 + (((l >> 4) ^ ((l >> 1) & 3)) * 16);
  // staging source: lane l covers row l>>2, global chunk (l&3) ^ X(l>>2)
  const int srow = l >> 2;
  const int scol = (((l & 3) ^ ((l >> 3) & 3)) * 16);

  if (tid < 128) keyR[tid] = key[rowBase + tid];
  else           keyC[tid - 128] = key[colBase + tid - 128];
  asm volatile("" ::: "memory");   // pin key ds_writes before the pipeline

  // per-wave staged bands: band = wid*2 + s (16 rows each)
  const size_t aOff0 = (size_t)(rowBase + (wid * 2 + 0) * 16 + srow) * ND + scol;
  const size_t aOff1 = (size_t)(rowBase + (wid * 2 + 1) * 16 + srow) * ND + scol;
  const size_t bOff0 = (size_t)(colBase + (wid * 2 + 0) * 16 + srow) * ND + scol;
  const size_t bOff1 = (size_t)(colBase + (wid * 2 + 1) * 16 + srow) * ND + scol;
  const int dst0 = (wid * 2 + 0) * 1024 + l * 16;
  const int dst1 = (wid * 2 + 1) * 1024 + l * 16;

#define STAGE(buf, k0)                                                         \
  do {                                                                         \
    __builtin_amdgcn_global_load_lds(                                          \
        (const __attribute__((address_space(1))) void*)(emb8 + aOff0 + (k0)),  \
        (__attribute__((address_space(3))) void*)&sT[buf][0][dst0], 16, 0, 0); \
    __builtin_amdgcn_global_load_lds(                                          \
        (const __attribute__((address_space(1))) void*)(emb8 + aOff1 + (k0)),  \
        (__attribute__((address_space(3))) void*)&sT[buf][0][dst1], 16, 0, 0); \
    __builtin_amdgcn_global_load_lds(                                          \
        (const __attribute__((address_space(1))) void*)(emb8 + bOff0 + (k0)),  \
        (__attribute__((address_space(3))) void*)&sT[buf][1][dst0], 16, 0, 0); \
    __builtin_amdgcn_global_load_lds(                                          \
        (const __attribute__((address_space(1))) void*)(emb8 + bOff1 + (k0)),  \
        (__attribute__((address_space(3))) void*)&sT[buf][1][dst1], 16, 0, 0); \
  } while (0)

  // prologue: stage K-tile 0 into buf 0
  STAGE(0, 0);

  f32x4 acc[4][4] = {};
  int rb = 0, wb = 1;            // read buffer, write buffer (wave-uniform)

#pragma unroll 1
  for (int kt = 0; kt < 16; ++kt) {
    if (kt < 15) {               // stage K-tile kt+1 into buf wb
      STAGE(wb, (kt + 1) * 64);
      asm volatile("s_waitcnt vmcnt(4) lgkmcnt(0)" ::: "memory");
    } else {
      asm volatile("s_waitcnt vmcnt(0) lgkmcnt(0)" ::: "memory");
    }
    __builtin_amdgcn_s_barrier();
    asm volatile("" ::: "memory");   // keep ds_reads below the barrier

    const unsigned char* cA = &sT[rb][0][0];
    const unsigned char* cB = &sT[rb][1][0];
    lx2 a2[4], b2[4];
#pragma unroll
    for (int m = 0; m < 4; ++m)
      a2[m] = *(const lx2*)&cA[(wr * 4 + m) * 1024 + fragOff];
#pragma unroll
    for (int n = 0; n < 4; ++n)
      b2[n] = *(const lx2*)&cB[(wc * 4 + n) * 1024 + fragOff];
    __builtin_amdgcn_s_setprio(1);
#pragma unroll
    for (int m = 0; m < 4; ++m)
#pragma unroll
      for (int n = 0; n < 4; ++n)
        acc[m][n] = __builtin_amdgcn_mfma_f32_16x16x32_fp8_fp8(a2[m][0], b2[n][0], acc[m][n], 0, 0, 0);
#pragma unroll
    for (int m = 0; m < 4; ++m)
#pragma unroll
      for (int n = 0; n < 4; ++n)
        acc[m][n] = __builtin_amdgcn_mfma_f32_16x16x32_fp8_fp8(a2[m][1], b2[n][1], acc[m][n], 0, 0, 0);
    __builtin_amdgcn_s_setprio(0);

    rb = (rb == 2) ? 0 : rb + 1;
    wb = (wb == 2) ? 0 : wb + 1;
  }
#undef STAGE

  // epilogue: C/D layout col = lane&15, row = (lane>>4)*4 + reg
  float cse[4] = {0.f, 0.f, 0.f, 0.f};   // per-col partials (off-diag only)
  float cnu[4] = {0.f, 0.f, 0.f, 0.f};
#pragma unroll
  for (int m = 0; m < 4; ++m) {
#pragma unroll
    for (int r4 = 0; r4 < 4; ++r4) {
      int li = wr * 64 + m * 16 + (l >> 4) * 4 + r4;
      int gi = rowBase + li;
      int krow = keyR[li];
      float se = 0.f, nu = 0.f;
#pragma unroll
      for (int n = 0; n < 4; ++n) {
        int lj = wc * 64 + n * 16 + (l & 15);
        int gj = colBase + lj;
        float e = __expf(acc[m][n][r4] * EXPSCALE);
        if (gi == gj) e = 0.f;          // only possible on diagonal tiles
        bool match = (krow >= 0) && (krow == keyC[lj]);
        se += e;
        if (match) nu += e;
        if (!diag) {
          cse[n] += e;
          if (match) cnu[n] += e;
        }
      }
#pragma unroll
      for (int off = 8; off; off >>= 1) {
        se += __shfl_xor(se, off, 16);
        nu += __shfl_xor(nu, off, 16);
      }
      if ((l & 15) == 0) {
        atomicAdd(&sum_exp[gi], se);
        if (nu != 0.f) atomicAdd(&numer[gi], nu);
      }
    }
  }
  if (!diag) {
#pragma unroll
    for (int n = 0; n < 4; ++n) {
      cse[n] += __shfl_xor(cse[n], 16);
      cse[n] += __shfl_xor(cse[n], 32);
      cnu[n] += __shfl_xor(cnu[n], 16);
      cnu[n] += __shfl_xor(cnu[n], 32);
    }
    if (l < 16) {
#pragma unroll
      for (int n = 0; n < 4; ++n) {
        int gj = colBase + wc * 64 + n * 16 + l;
        atomicAdd(&sum_exp[gj], cse[n]);
        if (cnu[n] != 0.f) atomicAdd(&numer[gj], cnu[n]);
      }
    }
  }
}

// ---------------- fallback 128^2 fused kernel (small-ws path, bf16) --------
__global__ __launch_bounds__(256, 4)
void gemm_fused_f32_kernel(const float* __restrict__ embF,
                           const int* __restrict__ key,
                           float* __restrict__ sum_exp,
                           float* __restrict__ numer) {
  __shared__ __bf16 sA[128 * 64];
  __shared__ __bf16 sB[128 * 64];
  __shared__ int keyR[128], keyC[128];

  const int t = blockIdx.x;
  int r = (int)((sqrtf(8.f * (float)t + 1.f) - 1.f) * 0.5f);
  while ((r + 1) * (r + 2) / 2 <= t) ++r;
  while (r * (r + 1) / 2 > t) --r;
  const int bx = r;
  const int by = t - r * (r + 1) / 2;
  const bool diag = (bx == by);

  const int tid = threadIdx.x;
  const int wid = tid >> 6;
  const int l   = tid & 63;
  const int wr  = wid >> 1;
  const int wc  = wid & 1;
  const int rowBase = by * 128;
  const int colBase = bx * 128;

  if (tid < 128) keyR[tid] = key[rowBase + tid];
  else           keyC[tid - 128] = key[colBase + tid - 128];

  f32x4 acc[4][4] = {};

  for (int k0 = 0; k0 < ND; k0 += 64) {
    __syncthreads();
#pragma unroll
    for (int c = 0; c < 4; ++c) {
      int chunk = tid + c * 256;
      int row = chunk >> 3;
      int ko  = (chunk & 7) * 8;
      const float* gfa = embF + (size_t)(rowBase + row) * ND + k0 + ko;
      const float* gfb = embF + (size_t)(colBase + row) * ND + k0 + ko;
      float4 a0 = *(const float4*)gfa;
      float4 a1 = *(const float4*)(gfa + 4);
      float4 b0 = *(const float4*)gfb;
      float4 b1 = *(const float4*)(gfb + 4);
      *(bf16x8*)&sA[row * 64 + ko] = cvt8(a0, a1);
      *(bf16x8*)&sB[row * 64 + ko] = cvt8(b0, b1);
    }
    __syncthreads();

#pragma unroll
    for (int kk = 0; kk < 2; ++kk) {
      bf16x8 af[4], bfr[4];
#pragma unroll
      for (int m = 0; m < 4; ++m)
        af[m] = *(const bf16x8*)&sA[(wr * 64 + m * 16 + (l & 15)) * 64 + kk * 32 + (l >> 4) * 8];
#pragma unroll
      for (int n = 0; n < 4; ++n)
        bfr[n] = *(const bf16x8*)&sB[(wc * 64 + n * 16 + (l & 15)) * 64 + kk * 32 + (l >> 4) * 8];
#pragma unroll
      for (int m = 0; m < 4; ++m)
#pragma unroll
        for (int n = 0; n < 4; ++n)
          acc[m][n] = __builtin_amdgcn_mfma_f32_16x16x32_bf16(af[m], bfr[n], acc[m][n], 0, 0, 0);
    }
  }

  float cse[4] = {0.f, 0.f, 0.f, 0.f};
  float cnu[4] = {0.f, 0.f, 0.f, 0.f};
#pragma unroll
  for (int m = 0; m < 4; ++m) {
#pragma unroll
    for (int r4 = 0; r4 < 4; ++r4) {
      int li = wr * 64 + m * 16 + (l >> 4) * 4 + r4;
      int gi = rowBase + li;
      int krow = keyR[li];
      float se = 0.f, nu = 0.f;
#pragma unroll
      for (int n = 0; n < 4; ++n) {
        int lj = wc * 64 + n * 16 + (l & 15);
        int gj = colBase + lj;
        float e = __expf(acc[m][n][r4] * SCALE);
        if (gi == gj) e = 0.f;
        bool match = (krow >= 0) && (krow == keyC[lj]);
        se += e;
        if (match) nu += e;
        if (!diag) {
          cse[n] += e;
          if (match) cnu[n] += e;
        }
      }
#pragma unroll
      for (int off = 8; off; off >>= 1) {
        se += __shfl_xor(se, off, 16);
        nu += __shfl_xor(nu, off, 16);
      }
      if ((l & 15) == 0) {
        atomicAdd(&sum_exp[gi], se);
        if (nu != 0.f) atomicAdd(&numer[gi], nu);
      }
    }
  }
  if (!diag) {
#pragma unroll
    for (int n = 0; n < 4; ++n) {
      cse[n] += __shfl_xor(cse[n], 16);
      cse[n] += __shfl_xor(cse[n], 32);
      cnu[n] += __shfl_xor(cnu[n], 16);
      cnu[n] += __shfl_xor(cnu[n], 32);
    }
    if (l < 16) {
#pragma unroll
      for (int n = 0; n < 4; ++n) {
        int gj = colBase + wc * 64 + n * 16 + l;
        atomicAdd(&sum_exp[gj], cse[n]);
        if (cnu[n] != 0.f) atomicAdd(&numer[gj], cnu[n]);
      }
    }
  }
}

// ---------------- finalize: histogram -> has_pos, losses, reductions -------
__global__ void finalize_kernel(const float* __restrict__ sum_exp,
                                const float* __restrict__ numer,
                                const int* __restrict__ key,
                                float* __restrict__ out) {
  __shared__ int cnt[128];
  __shared__ float wsum[16];
  __shared__ int wcnt[16];
  int tid = threadIdx.x;      // 1024 threads
  if (tid < 128) cnt[tid] = 0;
  __syncthreads();
  for (int i = tid; i < NB; i += 1024) {
    int k = key[i];
    if (k >= 0) atomicAdd(&cnt[k], 1);
  }
  __syncthreads();
  float ls = 0.f; int np = 0;
  for (int i = tid; i < NB; i += 1024) {
    int k = key[i];
    if (k >= 0 && cnt[k] >= 2) {
      np++;
      ls += logf(sum_exp[i] + 1e-8f) - logf(numer[i]);
    }
  }
  for (int off = 32; off; off >>= 1) {
    ls += __shfl_down(ls, off, 64);
    np += __shfl_down(np, off, 64);
  }
  int w = tid >> 6;
  if ((tid & 63) == 0) { wsum[w] = ls; wcnt[w] = np; }
  __syncthreads();
  if (tid == 0) {
    float s = 0.f; int n = 0;
    for (int i = 0; i < 16; ++i) { s += wsum[i]; n += wcnt[i]; }
    out[0] = (n > 0) ? (s / (float)n) : 0.f;
    out[1] = (float)n;
  }
}

// ---------------------------------------------------------------------------
#define NT128 64
#define NTRI128 (NT128 * (NT128 + 1) / 2) // 2080

extern "C" void kernel_launch(void* const* d_in, const int* in_sizes, int n_in,
                              void* d_out, int out_size, void* d_ws, size_t ws_size,
                              hipStream_t stream) {
  const float* emb = (const float*)d_in[0];
  const void* rel  = d_in[1];
  const void* ist  = d_in[2];
  float* out = (float*)d_out;

  const size_t emb8Bytes = (size_t)NB * ND;      // 8 MiB fp8
  const size_t smallBytes = (size_t)NB * 4 * 3;  // 96 KiB

  char* ws = (char*)d_ws;
  if (ws_size >= emb8Bytes + smallBytes) {
    unsigned char* emb8 = (unsigned char*)ws;
    float* sum_exp = (float*)(ws + emb8Bytes);
    float* numer   = sum_exp + NB;
    int*   key     = (int*)(numer + NB);
    prep_kernel<<<4096, 256, 0, stream>>>(emb, rel, ist, emb8, sum_exp, numer, key);
    gemm_f8v_kernel<<<NTRI128, 256, 0, stream>>>(emb8, key, sum_exp, numer);
    finalize_kernel<<<1, 1024, 0, stream>>>(sum_exp, numer, key, out);
  } else {
    float* sum_exp = (float*)ws;
    float* numer   = sum_exp + NB;
    int*   key     = (int*)(numer + NB);
    prep_small_kernel<<<32, 256, 0, stream>>>(rel, ist, sum_exp, numer, key);
    gemm_fused_f32_kernel<<<NTRI128, 256, 0, stream>>>(emb, key, sum_exp, numer);
    finalize_kernel<<<1, 1024, 0, stream>>>(sum_exp, numer, key, out);
  }
}